// Round 3
// baseline (107.619 us; speedup 1.0000x reference)
//
#include <hip/hip_runtime.h>

// CLRNetIoULoss: pred/target (NL, 72) fp32 -> scalar fp32 loss.
// R3: pair-of-float4 per thread (32B/lane coalesced; 18 f4/row even -> a pair
// never crosses a row). 9 partials/row staged in LDS as SoA (conflict-free),
// 18.4 KB/block -> 8 blocks/CU = 32 waves/CU (full wave cap).
// so = 2W*tp - D ; su = 2W*tp + D.

#define NR    72
#define NP2   9                // float4-PAIRS per row
#define BLOCK 256
#define RPB   256              // rows per block
#define P2PB  (RPB * NP2)      // 2304 pairs per array per block

__global__ __launch_bounds__(BLOCK, 8) void clrnet_iou_rows(
    const float4* __restrict__ pred4,
    const float4* __restrict__ tgt4,
    float* __restrict__ partial,   // one float per block
    int nl) {
  __shared__ float sd_[P2PB];   // per-pair D = sum|p-t| over both-valid
  __shared__ int   sc_[P2PB];   // per-pair tp | er<<8
  __shared__ float ws[BLOCK / 64];

  const long long p2_total = (long long)nl * NP2;
  const long long base2 = (long long)blockIdx.x * P2PB;

  // ---- Phase 1: coalesced global (32B/lane) -> per-pair partials in LDS ----
#pragma unroll
  for (int k = 0; k < NP2; ++k) {
    const int iloc = k * BLOCK + threadIdx.x;          // 0..2303, linear
    const long long g2 = base2 + iloc;
    float d = 0.0f;
    int   c = 0;
    if (g2 < p2_total) {
      const float4* pp = pred4 + 2 * g2;
      const float4* tt = tgt4  + 2 * g2;
      float4 p0 = pp[0], p1 = pp[1];
      float4 t0 = tt[0], t1 = tt[1];
#pragma unroll
      for (int j = 0; j < 4; ++j) {
        float pv = (&p0.x)[j], tv = (&t0.x)[j];
        bool vp = (pv >= 0.0f) & (pv < 1.0f);
        bool vt = (tv >= 0.0f) & (tv < 1.0f);
        bool both = vp & vt;
        d += both ? fabsf(pv - tv) : 0.0f;
        c += (both ? 1 : 0) + ((vp != vt) ? 256 : 0);
      }
#pragma unroll
      for (int j = 0; j < 4; ++j) {
        float pv = (&p1.x)[j], tv = (&t1.x)[j];
        bool vp = (pv >= 0.0f) & (pv < 1.0f);
        bool vt = (tv >= 0.0f) & (tv < 1.0f);
        bool both = vp & vt;
        d += both ? fabsf(pv - tv) : 0.0f;
        c += (both ? 1 : 0) + ((vp != vt) ? 256 : 0);
      }
    }
    sd_[iloc] = d;     // linear in tid -> conflict-free
    sc_[iloc] = c;
  }
  __syncthreads();

  // ---- Phase 2: one thread per row, nonlinear part ----
  float loss = 0.0f;
  const long long row = (long long)blockIdx.x * RPB + threadIdx.x;
  if (row < nl) {
    float D = 0.0f;
    int   c = 0;
    const int rbase = threadIdx.x * NP2;   // stride 9 dwords: gcd(9,32)=1
#pragma unroll
    for (int j = 0; j < NP2; ++j) {
      D += sd_[rbase + j];
      c += sc_[rbase + j];
    }
    const int tp = c & 0xff;
    const int er = c >> 8;
    const float W2 = 2.0f * (15.0f / 800.0f);
    const float ftp = (float)tp;
    float so = W2 * ftp - D;
    float su = W2 * ftp + D;
    float iou = so / (su + 1e-9f);
    if (tp > er && er > 0) {
      iou *= (1.0f - (float)er / (ftp + 1e-9f));
    }
    loss = 1.0f - iou;
  }

  // ---- block reduce of loss ----
#pragma unroll
  for (int off = 32; off > 0; off >>= 1)
    loss += __shfl_down(loss, off, 64);

  const int lane = threadIdx.x & 63;
  const int wid  = threadIdx.x >> 6;
  if (lane == 0) ws[wid] = loss;
  __syncthreads();
  if (threadIdx.x == 0) {
    float s = 0.0f;
#pragma unroll
    for (int w = 0; w < BLOCK / 64; ++w) s += ws[w];
    partial[blockIdx.x] = s;
  }
}

__global__ __launch_bounds__(256) void clrnet_iou_finish(
    const float* __restrict__ partial, int nparts, float* __restrict__ out,
    float inv_nl) {
  // single block; fp64 accumulation for deterministic, accurate final sum
  double acc = 0.0;
  for (int i = threadIdx.x; i < nparts; i += 256)
    acc += (double)partial[i];

  __shared__ double sd[256];
  sd[threadIdx.x] = acc;
  __syncthreads();
#pragma unroll
  for (int s = 128; s > 0; s >>= 1) {
    if (threadIdx.x < s) sd[threadIdx.x] += sd[threadIdx.x + s];
    __syncthreads();
  }
  if (threadIdx.x == 0) {
    const double LOSS_WEIGHT = 1.0;
    out[0] = (float)(sd[0] * (double)inv_nl * LOSS_WEIGHT);
  }
}

extern "C" void kernel_launch(void* const* d_in, const int* in_sizes, int n_in,
                              void* d_out, int out_size, void* d_ws, size_t ws_size,
                              hipStream_t stream) {
  const float4* pred4 = (const float4*)d_in[0];
  const float4* tgt4  = (const float4*)d_in[1];
  float* out = (float*)d_out;

  const int nl = in_sizes[0] / NR;               // 1,000,000
  const int nblocks = (nl + RPB - 1) / RPB;      // 3907

  float* partial = (float*)d_ws;                 // nblocks floats of scratch

  clrnet_iou_rows<<<nblocks, BLOCK, 0, stream>>>(pred4, tgt4, partial, nl);
  clrnet_iou_finish<<<1, 256, 0, stream>>>(partial, nblocks, out,
                                           1.0f / (float)nl);
}